// Round 2
// 787.062 us; speedup vs baseline: 1.2843x; 1.2843x over previous
//
#include <hip/hip_runtime.h>

typedef unsigned short u16;
typedef __attribute__((ext_vector_type(8))) short short8;
typedef __attribute__((ext_vector_type(4))) float floatx4;
typedef __attribute__((ext_vector_type(4))) unsigned int uintx4;

#define B_    16
#define C_    512
#define N_    4096
#define NH_   8
#define HD_   64
#define MQKV  1536

union V16 { uintx4 u; u16 s[8]; short8 h; };

__device__ inline u16 f2bf(float f) {
  union { float f; unsigned int i; } c; c.f = f;
  unsigned int i = c.i;
  return (u16)((i + 0x7FFFu + ((i >> 16) & 1u)) >> 16);
}

// async global->LDS, 16B per lane; LDS dest must be wave-uniform-base + lane*16
__device__ __forceinline__ void gld16(const u16* g, u16* l) {
  __builtin_amdgcn_global_load_lds(
      (const __attribute__((address_space(1))) unsigned int*)g,
      (__attribute__((address_space(3))) unsigned int*)l, 16, 0, 0);
}

// ---------------- Kernel 1: GroupNorm stats -> per-(b,c) affine (f32 in) ----------------
__global__ __launch_bounds__(256) void gn_stats(const float* __restrict__ x,
    const float* __restrict__ gamma, const float* __restrict__ beta,
    float* __restrict__ s_arr, float* __restrict__ t_arr) {
  int b = blockIdx.x >> 5, g = blockIdx.x & 31;
  const floatx4* p = (const floatx4*)(x + (size_t)(b * C_ + g * 16) * N_);
  int tid = threadIdx.x;
  float sum = 0.f, ssq = 0.f;
  for (int it = 0; it < 64; ++it) {
    floatx4 v = p[tid + it * 256];
#pragma unroll
    for (int j = 0; j < 4; ++j) { float f = v[j]; sum += f; ssq += f * f; }
  }
#pragma unroll
  for (int off = 32; off > 0; off >>= 1) {
    sum += __shfl_down(sum, off);
    ssq += __shfl_down(ssq, off);
  }
  __shared__ float red[8];
  __shared__ float mv[2];
  int lane = tid & 63, wid = tid >> 6;
  if (lane == 0) { red[wid] = sum; red[wid + 4] = ssq; }
  __syncthreads();
  if (tid == 0) {
    float s = red[0] + red[1] + red[2] + red[3];
    float q = red[4] + red[5] + red[6] + red[7];
    float mean = s * (1.f / 65536.f);
    float var  = q * (1.f / 65536.f) - mean * mean;
    mv[0] = mean; mv[1] = rsqrtf(var + 1e-5f);
  }
  __syncthreads();
  if (tid < 16) {
    int c = g * 16 + tid;
    float ga = gamma[c], be = beta[c];
    float mean = mv[0], rstd = mv[1];
    s_arr[b * C_ + c] = ga * rstd;
    t_arr[b * C_ + c] = be - mean * rstd * ga;
  }
}

// ---------------- Kernel 1b: f32 -> bf16 convert (weights, one-time) ----------------
__global__ __launch_bounds__(256) void cvt_bf16(const float* __restrict__ src,
                                                u16* __restrict__ dst) {
  int i = blockIdx.x * 256 + threadIdx.x;
  const floatx4* s4 = (const floatx4*)src;
  floatx4 a = s4[2 * i], b = s4[2 * i + 1];
  V16 v;
#pragma unroll
  for (int j = 0; j < 4; ++j) { v.s[j] = f2bf(a[j]); v.s[4 + j] = f2bf(b[j]); }
  ((uintx4*)dst)[i] = v.u;
}

// ---- Kernel 1c: GN-apply + transpose: x[b][c][n] f32 -> xt[b][n][c] bf16 ----
// grid (N/64, C/64, Bc), block 256
__global__ __launch_bounds__(256) void gn_apply_t(const float* __restrict__ x,
    const float* __restrict__ s_arr, const float* __restrict__ t_arr,
    u16* __restrict__ xt, int b0) {
  __shared__ float T[64][65];
  int bz = blockIdx.z, gb = b0 + bz;
  int n0 = blockIdx.x * 64, c0 = blockIdx.y * 64;
  int tid = threadIdx.x;
  int cl = tid >> 4;          // 0..15
  int nl = (tid & 15) * 4;    // 0,4,..,60
  const float* xb = x + (size_t)bz * C_ * N_;
#pragma unroll
  for (int ci = 0; ci < 4; ++ci) {
    int c = c0 + cl + ci * 16;
    float s = s_arr[gb * C_ + c], t = t_arr[gb * C_ + c];
    floatx4 v = *(const floatx4*)(xb + (size_t)c * N_ + n0 + nl);
#pragma unroll
    for (int j = 0; j < 4; ++j) T[cl + ci * 16][nl + j] = s * v[j] + t;
  }
  __syncthreads();
  int n = tid >> 2, cc = (tid & 3) * 16;
  V16 a, b;
#pragma unroll
  for (int j = 0; j < 8; ++j) a.s[j] = f2bf(T[cc + j][n]);
#pragma unroll
  for (int j = 0; j < 8; ++j) b.s[j] = f2bf(T[cc + 8 + j][n]);
  uintx4* dst = (uintx4*)(xt + (size_t)bz * N_ * C_ + (size_t)(n0 + n) * C_ + c0 + cc);
  dst[0] = a.u; dst[1] = b.u;
}

// ------- Kernel 2/5: out[bz][m][n] = A[m][k] * B[bz][n][k]^T  (both bf16 k-contig) ----
// m97-structure: 128x128 tile, global_load_lds w16, source-side XOR swizzle (key row&7)
__global__ __launch_bounds__(256) void gemm_bt(
    const u16* __restrict__ A, const u16* __restrict__ Bm,
    const float* __restrict__ bias, const float* __restrict__ resid,
    void* __restrict__ outv, int M, int doRes, int outF32) {
  __shared__ alignas(16) u16 As[128 * 64];
  __shared__ alignas(16) u16 Bs[128 * 64];
  int bz = blockIdx.z;
  int m0 = blockIdx.y * 128, n0 = blockIdx.x * 128;
  int tid = threadIdx.x, lane = tid & 63, wid = tid >> 6;
  int quad = lane >> 4, l15 = lane & 15;
  int wm = (wid >> 1) * 64, wn = (wid & 1) * 64;
  int sr = tid >> 3, sc = tid & 7;   // staging: row, chunk-of-8
  const u16* Bb = Bm + (size_t)bz * ((size_t)N_ * C_);
  floatx4 acc[4][4];
#pragma unroll
  for (int i = 0; i < 4; ++i)
#pragma unroll
    for (int j = 0; j < 4; ++j) acc[i][j] = (floatx4)0.f;

  for (int kt = 0; kt < 8; ++kt) {
    // stage A/B tiles: LDS linear, global source pre-swizzled (chunk ^= row&7)
#pragma unroll
    for (int i = 0; i < 4; ++i) {
      int rr = sr + i * 32;
      int cc = sc ^ (rr & 7);
      gld16(A  + (size_t)(m0 + rr) * C_ + kt * 64 + cc * 8, &As[rr * 64 + sc * 8]);
      gld16(Bb + (size_t)(n0 + rr) * C_ + kt * 64 + cc * 8, &Bs[rr * 64 + sc * 8]);
    }
    __syncthreads();
#pragma unroll
    for (int ks = 0; ks < 2; ++ks) {
      short8 af[4], bf8[4];
#pragma unroll
      for (int mi = 0; mi < 4; ++mi) {
        int row = wm + mi * 16 + l15;
        int kc = (ks * 4 + quad) ^ (row & 7);
        af[mi] = *(const short8*)&As[row * 64 + kc * 8];
      }
#pragma unroll
      for (int ni = 0; ni < 4; ++ni) {
        int row = wn + ni * 16 + l15;
        int kc = (ks * 4 + quad) ^ (row & 7);
        bf8[ni] = *(const short8*)&Bs[row * 64 + kc * 8];
      }
#pragma unroll
      for (int mi = 0; mi < 4; ++mi)
#pragma unroll
        for (int ni = 0; ni < 4; ++ni)
          acc[mi][ni] = __builtin_amdgcn_mfma_f32_16x16x32_bf16(af[mi], bf8[ni], acc[mi][ni], 0, 0, 0);
    }
    __syncthreads();
  }
  // epilogue (C/D layout: col=l15, row=quad*4+r)
#pragma unroll
  for (int mi = 0; mi < 4; ++mi) {
#pragma unroll
    for (int ni = 0; ni < 4; ++ni) {
#pragma unroll
      for (int r = 0; r < 4; ++r) {
        int o = m0 + wm + mi * 16 + quad * 4 + r;
        int n = n0 + wn + ni * 16 + l15;
        float vv = acc[mi][ni][r] + bias[o];
        size_t oidx = ((size_t)bz * M + o) * N_ + n;
        if (doRes) vv += resid[oidx];
        if (outF32) ((float*)outv)[oidx] = vv;
        else        ((u16*)outv)[oidx]   = f2bf(vv);
      }
    }
  }
}

// ---------------- Kernel 3: S = q k^T (over N), softmax rows -> attn f32 ----------------
__global__ __launch_bounds__(256) void qk_softmax(const u16* __restrict__ qkv,
                                                  float* __restrict__ attn) {
  int h = blockIdx.x, bz = blockIdx.y;
  const u16* qb = qkv + ((size_t)bz * MQKV + h * HD_) * N_;
  const u16* kb = qkv + ((size_t)bz * MQKV + C_ + h * HD_) * N_;
  int tid = threadIdx.x, lane = tid & 63, wid = tid >> 6;
  int quad = lane >> 4, l15 = lane & 15;
  floatx4 acc[4][4];
#pragma unroll
  for (int i = 0; i < 4; ++i)
#pragma unroll
    for (int j = 0; j < 4; ++j) acc[i][j] = (floatx4)0.f;

  for (int ks = 0; ks < 32; ++ks) {
    int n = wid * 1024 + ks * 32 + quad * 8;
    short8 af[4], bf8[4];
#pragma unroll
    for (int mi = 0; mi < 4; ++mi)
      af[mi] = *(const short8*)(qb + (size_t)(mi * 16 + l15) * N_ + n);
#pragma unroll
    for (int ni = 0; ni < 4; ++ni)
      bf8[ni] = *(const short8*)(kb + (size_t)(ni * 16 + l15) * N_ + n);
#pragma unroll
    for (int mi = 0; mi < 4; ++mi)
#pragma unroll
      for (int ni = 0; ni < 4; ++ni)
        acc[mi][ni] = __builtin_amdgcn_mfma_f32_16x16x32_bf16(af[mi], bf8[ni], acc[mi][ni], 0, 0, 0);
  }
  __shared__ float S[64 * 65];
  for (int i = tid; i < 64 * 65; i += 256) S[i] = 0.f;
  __syncthreads();
#pragma unroll
  for (int mi = 0; mi < 4; ++mi)
#pragma unroll
    for (int ni = 0; ni < 4; ++ni)
#pragma unroll
      for (int r = 0; r < 4; ++r)
        atomicAdd(&S[(mi * 16 + quad * 4 + r) * 65 + ni * 16 + l15], acc[mi][ni][r]);
  __syncthreads();
  if (tid < 64) {
    float mx = -1e30f;
    for (int j = 0; j < 64; ++j) mx = fmaxf(mx, S[tid * 65 + j]);
    float sum = 0.f;
    for (int j = 0; j < 64; ++j) sum += __expf((S[tid * 65 + j] - mx) * 0.125f);
    float inv = 1.f / sum;
    float* dst = attn + ((size_t)(bz * NH_ + h) * 64 + tid) * 64;
    for (int j = 0; j < 64; ++j) dst[j] = __expf((S[tid * 65 + j] - mx) * 0.125f) * inv;
  }
}

// ------- Kernel 4: O = attn * v, output TRANSPOSED ot[bz][n][c] bf16 (c = h*64+hd) -----
__global__ __launch_bounds__(256) void pv_kernel(const float* __restrict__ attn,
    const u16* __restrict__ qkv, u16* __restrict__ ot) {
  int nt = blockIdx.x, h = blockIdx.y, bz = blockIdx.z;
  int n0 = nt * 256;
  const u16* vb = qkv + ((size_t)bz * MQKV + 2 * C_ + h * HD_) * N_;
  __shared__ alignas(16) u16 Ps[64 * 72];
  __shared__ alignas(16) u16 Vs[256 * 72];
  int tid = threadIdx.x, lane = tid & 63, wid = tid >> 6;
  int quad = lane >> 4, l15 = lane & 15;
  const float* ab = attn + (size_t)(bz * NH_ + h) * 4096;
#pragma unroll
  for (int i = 0; i < 16; ++i) {
    int idx = tid + i * 256;
    int row = idx >> 6, col = idx & 63;
    Ps[row * 72 + col] = f2bf(ab[idx]);
  }
#pragma unroll
  for (int i = 0; i < 8; ++i) {
    int l = tid + i * 256;
    int ch = l >> 5, n8 = (l & 31) * 8;
    V16 v; v.u = *(const uintx4*)(vb + (size_t)ch * N_ + n0 + n8);
    int chunk = ch >> 3, clo = ch & 7;
#pragma unroll
    for (int j = 0; j < 8; ++j) {
      int nl = n8 + j;
      Vs[nl * 72 + (chunk ^ ((nl >> 3) & 7)) * 8 + clo] = v.s[j];
    }
  }
  __syncthreads();
  floatx4 acc[4][4];
#pragma unroll
  for (int i = 0; i < 4; ++i)
#pragma unroll
    for (int j = 0; j < 4; ++j) acc[i][j] = (floatx4)0.f;
#pragma unroll
  for (int ks = 0; ks < 2; ++ks) {
    short8 af[4], bf8[4];
    int ko = ks * 32 + quad * 8;
#pragma unroll
    for (int mi = 0; mi < 4; ++mi)
      af[mi] = *(const short8*)&Ps[(mi * 16 + l15) * 72 + ko];
    int chunk = ks * 4 + quad;
#pragma unroll
    for (int ni = 0; ni < 4; ++ni) {
      int nl = wid * 64 + ni * 16 + l15;
      bf8[ni] = *(const short8*)&Vs[nl * 72 + (chunk ^ ((nl >> 3) & 7)) * 8];
    }
#pragma unroll
    for (int mi = 0; mi < 4; ++mi)
#pragma unroll
      for (int ni = 0; ni < 4; ++ni)
        acc[mi][ni] = __builtin_amdgcn_mfma_f32_16x16x32_bf16(af[mi], bf8[ni], acc[mi][ni], 0, 0, 0);
  }
  // transpose epilogue via LDS (reuse Vs as Ls[256][64], XOR-swizzled chunks)
  __syncthreads();
  u16* Ls = Vs;
#pragma unroll
  for (int mi = 0; mi < 4; ++mi)
#pragma unroll
    for (int ni = 0; ni < 4; ++ni)
#pragma unroll
      for (int r = 0; r < 4; ++r) {
        int n  = wid * 64 + ni * 16 + l15;
        int hd = mi * 16 + quad * 4 + r;
        Ls[n * 64 + (((hd >> 3) ^ (n & 7)) * 8) + (hd & 7)] = f2bf(acc[mi][ni][r]);
      }
  __syncthreads();
  uintx4* dst = (uintx4*)(ot + ((size_t)bz * N_ + n0 + tid) * C_ + h * HD_);
#pragma unroll
  for (int k = 0; k < 8; ++k) {
    int kc = k ^ (tid & 7);
    dst[k] = *(const uintx4*)&Ls[tid * 64 + kc * 8];
  }
}

extern "C" void kernel_launch(void* const* d_in, const int* in_sizes, int n_in,
                              void* d_out, int out_size, void* d_ws, size_t ws_size,
                              hipStream_t stream) {
  const float* x      = (const float*)d_in[0];
  const float* gamma  = (const float*)d_in[1];
  const float* beta   = (const float*)d_in[2];
  const float* w_qkv  = (const float*)d_in[3];
  const float* b_qkv  = (const float*)d_in[4];
  const float* w_proj = (const float*)d_in[5];
  const float* b_proj = (const float*)d_in[6];
  float* out = (float*)d_out;

  // ws: s[16*512]f32 | t[16*512]f32 | wq[1536*512]bf16 | wp[512*512]bf16 |
  //     attn[Bc*8*64*64]f32 | xt[Bc*4096*512]bf16 (reused as o_t) | qkv[Bc*1536*4096]bf16
  const size_t fixed = (size_t)2 * B_ * C_ * 4 + (size_t)(MQKV + C_) * C_ * 2;
  const size_t per_batch = (size_t)NH_ * 64 * 64 * 4 + (size_t)N_ * C_ * 2 + (size_t)MQKV * N_ * 2;
  int Bc = 16;
  while (Bc > 1 && fixed + (size_t)Bc * per_batch > ws_size) Bc >>= 1;

  float* s_arr = (float*)d_ws;
  float* t_arr = s_arr + B_ * C_;
  u16* wq = (u16*)(t_arr + B_ * C_);
  u16* wp = wq + MQKV * C_;
  float* attn = (float*)(wp + C_ * C_);
  u16* xt  = (u16*)(attn + (size_t)Bc * NH_ * 64 * 64);
  u16* qkv = xt + (size_t)Bc * N_ * C_;

  gn_stats<<<dim3(B_ * 32), dim3(256), 0, stream>>>(x, gamma, beta, s_arr, t_arr);
  cvt_bf16<<<dim3(MQKV * C_ / 2048), dim3(256), 0, stream>>>(w_qkv, wq);
  cvt_bf16<<<dim3(C_ * C_ / 2048), dim3(256), 0, stream>>>(w_proj, wp);

  for (int b0 = 0; b0 < B_; b0 += Bc) {
    gn_apply_t<<<dim3(N_ / 64, C_ / 64, Bc), dim3(256), 0, stream>>>(
        x + (size_t)b0 * C_ * N_, s_arr, t_arr, xt, b0);
    gemm_bt<<<dim3(32, 12, Bc), dim3(256), 0, stream>>>(
        wq, xt, b_qkv, nullptr, qkv, MQKV, 0, 0);
    qk_softmax<<<dim3(NH_, Bc), dim3(256), 0, stream>>>(qkv, attn);
    pv_kernel<<<dim3(16, NH_, Bc), dim3(256), 0, stream>>>(attn, qkv, xt);  // xt := o_t
    gemm_bt<<<dim3(32, 4, Bc), dim3(256), 0, stream>>>(
        wp, xt, b_proj, x + (size_t)b0 * C_ * N_, out + (size_t)b0 * C_ * N_, C_, 1, 1);
  }
}

// Round 5
// 698.230 us; speedup vs baseline: 1.4477x; 1.1272x over previous
//
#include <hip/hip_runtime.h>

typedef unsigned short u16;
typedef __attribute__((ext_vector_type(8))) short short8;
typedef __attribute__((ext_vector_type(4))) float floatx4;
typedef __attribute__((ext_vector_type(4))) unsigned int uintx4;

#define B_    16
#define C_    512
#define N_    4096
#define NH_   8
#define HD_   64
#define MQKV  1536
#define NSPL  8

union V16 { uintx4 u; u16 s[8]; short8 h; };

__device__ inline u16 f2bf(float f) {
  union { float f; unsigned int i; } c; c.f = f;
  unsigned int i = c.i;
  return (u16)((i + 0x7FFFu + ((i >> 16) & 1u)) >> 16);
}

// async global->LDS, 16B per lane; LDS dest must be wave-uniform-base + lane*16
__device__ __forceinline__ void gld16(const u16* g, u16* l) {
  __builtin_amdgcn_global_load_lds(
      (const __attribute__((address_space(1))) unsigned int*)g,
      (__attribute__((address_space(3))) unsigned int*)l, 16, 0, 0);
}

// ---------------- Kernel 1: GroupNorm stats -> per-(b,c) affine (f32 in) ----------------
__global__ __launch_bounds__(256) void gn_stats(const float* __restrict__ x,
    const float* __restrict__ gamma, const float* __restrict__ beta,
    float* __restrict__ s_arr, float* __restrict__ t_arr) {
  int b = blockIdx.x >> 5, g = blockIdx.x & 31;
  const floatx4* p = (const floatx4*)(x + (size_t)(b * C_ + g * 16) * N_);
  int tid = threadIdx.x;
  float sum = 0.f, ssq = 0.f;
  for (int it = 0; it < 64; ++it) {
    floatx4 v = p[tid + it * 256];
#pragma unroll
    for (int j = 0; j < 4; ++j) { float f = v[j]; sum += f; ssq += f * f; }
  }
#pragma unroll
  for (int off = 32; off > 0; off >>= 1) {
    sum += __shfl_down(sum, off);
    ssq += __shfl_down(ssq, off);
  }
  __shared__ float red[8];
  __shared__ float mv[2];
  int lane = tid & 63, wid = tid >> 6;
  if (lane == 0) { red[wid] = sum; red[wid + 4] = ssq; }
  __syncthreads();
  if (tid == 0) {
    float s = red[0] + red[1] + red[2] + red[3];
    float q = red[4] + red[5] + red[6] + red[7];
    float mean = s * (1.f / 65536.f);
    float var  = q * (1.f / 65536.f) - mean * mean;
    mv[0] = mean; mv[1] = rsqrtf(var + 1e-5f);
  }
  __syncthreads();
  if (tid < 16) {
    int c = g * 16 + tid;
    float ga = gamma[c], be = beta[c];
    float mean = mv[0], rstd = mv[1];
    s_arr[b * C_ + c] = ga * rstd;
    t_arr[b * C_ + c] = be - mean * rstd * ga;
  }
}

// ---------------- Kernel 1b: f32 -> bf16 convert (weights, one-time) ----------------
__global__ __launch_bounds__(256) void cvt_bf16(const float* __restrict__ src,
                                                u16* __restrict__ dst) {
  int i = blockIdx.x * 256 + threadIdx.x;
  const floatx4* s4 = (const floatx4*)src;
  floatx4 a = s4[2 * i], b = s4[2 * i + 1];
  V16 v;
#pragma unroll
  for (int j = 0; j < 4; ++j) { v.s[j] = f2bf(a[j]); v.s[4 + j] = f2bf(b[j]); }
  ((uintx4*)dst)[i] = v.u;
}

// ---- Kernel 1c: GN-apply + transpose: x[b][c][n] f32 -> xt[b][n][c] bf16 ----
__global__ __launch_bounds__(256) void gn_apply_t(const float* __restrict__ x,
    const float* __restrict__ s_arr, const float* __restrict__ t_arr,
    u16* __restrict__ xt, int b0) {
  __shared__ float T[64][65];
  int bz = blockIdx.z, gb = b0 + bz;
  int n0 = blockIdx.x * 64, c0 = blockIdx.y * 64;
  int tid = threadIdx.x;
  int cl = tid >> 4;
  int nl = (tid & 15) * 4;
  const float* xb = x + (size_t)bz * C_ * N_;
#pragma unroll
  for (int ci = 0; ci < 4; ++ci) {
    int c = c0 + cl + ci * 16;
    float s = s_arr[gb * C_ + c], t = t_arr[gb * C_ + c];
    floatx4 v = *(const floatx4*)(xb + (size_t)c * N_ + n0 + nl);
#pragma unroll
    for (int j = 0; j < 4; ++j) T[cl + ci * 16][nl + j] = s * v[j] + t;
  }
  __syncthreads();
  int n = tid >> 2, cc = (tid & 3) * 16;
  V16 a, b;
#pragma unroll
  for (int j = 0; j < 8; ++j) a.s[j] = f2bf(T[cc + j][n]);
#pragma unroll
  for (int j = 0; j < 8; ++j) b.s[j] = f2bf(T[cc + 8 + j][n]);
  uintx4* dst = (uintx4*)(xt + (size_t)bz * N_ * C_ + (size_t)(n0 + n) * C_ + c0 + cc);
  dst[0] = a.u; dst[1] = b.u;
}

// ------- Kernel 2/5: out[bz][m][n] = A[m][k] * B[bz][n][k]^T  (both bf16 k-contig) ----
// 128x128 tile, global_load_lds w16, source-side XOR swizzle; LDS-transposed epilogue.
__global__ __launch_bounds__(256) void gemm_bt(
    const u16* __restrict__ A, const u16* __restrict__ Bm,
    const float* __restrict__ bias, const float* __restrict__ resid,
    void* __restrict__ outv, int M, int doRes, int outF32) {
  __shared__ alignas(16) u16 smem[128 * 64 * 2];   // As | Bs, reused by epilogue
  u16* As = smem;
  u16* Bs = smem + 128 * 64;
  int bz = blockIdx.z;
  int m0 = blockIdx.y * 128, n0 = blockIdx.x * 128;
  int tid = threadIdx.x, lane = tid & 63, wid = tid >> 6;
  int quad = lane >> 4, l15 = lane & 15;
  int wm = (wid >> 1) * 64, wn = (wid & 1) * 64;
  int sr = tid >> 3, sc = tid & 7;
  const u16* Bb = Bm + (size_t)bz * ((size_t)N_ * C_);
  floatx4 acc[4][4];
#pragma unroll
  for (int i = 0; i < 4; ++i)
#pragma unroll
    for (int j = 0; j < 4; ++j) acc[i][j] = (floatx4)0.f;

  for (int kt = 0; kt < 8; ++kt) {
#pragma unroll
    for (int i = 0; i < 4; ++i) {
      int rr = sr + i * 32;
      int cc = sc ^ (rr & 7);
      gld16(A  + (size_t)(m0 + rr) * C_ + kt * 64 + cc * 8, &As[rr * 64 + sc * 8]);
      gld16(Bb + (size_t)(n0 + rr) * C_ + kt * 64 + cc * 8, &Bs[rr * 64 + sc * 8]);
    }
    __syncthreads();
#pragma unroll
    for (int ks = 0; ks < 2; ++ks) {
      short8 af[4], bf8[4];
#pragma unroll
      for (int mi = 0; mi < 4; ++mi) {
        int row = wm + mi * 16 + l15;
        int kc = (ks * 4 + quad) ^ (row & 7);
        af[mi] = *(const short8*)&As[row * 64 + kc * 8];
      }
#pragma unroll
      for (int ni = 0; ni < 4; ++ni) {
        int row = wn + ni * 16 + l15;
        int kc = (ks * 4 + quad) ^ (row & 7);
        bf8[ni] = *(const short8*)&Bs[row * 64 + kc * 8];
      }
#pragma unroll
      for (int mi = 0; mi < 4; ++mi)
#pragma unroll
        for (int ni = 0; ni < 4; ++ni)
          acc[mi][ni] = __builtin_amdgcn_mfma_f32_16x16x32_bf16(af[mi], bf8[ni], acc[mi][ni], 0, 0, 0);
    }
    __syncthreads();
  }
  // ---- epilogue: LDS transpose -> vectorized 16B global stores ----
  if (!outF32) {
    // bf16 out: 128x128 u16 tile, 16B-chunk XOR swizzle (chunk^(row&7) in low 3 bits)
    u16* E = smem;
#pragma unroll
    for (int mi = 0; mi < 4; ++mi)
#pragma unroll
      for (int ni = 0; ni < 4; ++ni)
#pragma unroll
        for (int r = 0; r < 4; ++r) {
          int row = wm + mi * 16 + quad * 4 + r;
          int col = wn + ni * 16 + l15;
          int ch = col >> 3;
          int cs = (ch & 8) | ((ch & 7) ^ (row & 7));
          E[row * 128 + cs * 8 + (col & 7)] = f2bf(acc[mi][ni][r] + bias[m0 + row]);
        }
    __syncthreads();
    int row = tid >> 1, half = tid & 1;
    u16* orow = (u16*)outv + ((size_t)bz * M + m0 + row) * N_ + n0 + half * 64;
#pragma unroll
    for (int k = 0; k < 8; ++k) {
      int cs = (half * 8) | (k ^ (row & 7));
      *(uintx4*)(orow + k * 8) = *(const uintx4*)&E[row * 128 + cs * 8];
    }
  } else {
    // f32 out: two passes of 64 rows x 128 cols (32 KB each), 16B-chunk XOR swizzle
    float* E = (float*)smem;
#pragma unroll
    for (int p = 0; p < 2; ++p) {
#pragma unroll
      for (int q = 0; q < 2; ++q)
#pragma unroll
        for (int ni = 0; ni < 4; ++ni)
#pragma unroll
          for (int r = 0; r < 4; ++r) {
            int mi = p * 2 + q;
            int lr = (wid >> 1) * 32 + q * 16 + quad * 4 + r;
            int col = wn + ni * 16 + l15;
            int ch = col >> 2;
            int cs = (ch & ~7) | ((ch & 7) ^ (lr & 7));
            E[lr * 128 + cs * 4 + (col & 3)] =
                acc[mi][ni][r] + bias[m0 + wm + mi * 16 + quad * 4 + r];
          }
      __syncthreads();
      // store: 64 rows x 128 cols, 256 threads -> row = tid>>2, 8 x float4 each
      int lr = tid >> 2, qt = tid & 3;
      int o = m0 + (lr >> 5) * 64 + p * 32 + (lr & 31);
      size_t obase = ((size_t)bz * M + o) * N_ + n0 + qt * 4;
#pragma unroll
      for (int k = 0; k < 8; ++k) {
        int ch = k * 4 + qt;
        int cs = (ch & ~7) | ((ch & 7) ^ (lr & 7));
        floatx4 v = *(const floatx4*)&E[lr * 128 + cs * 4];
        if (doRes) v += *(const floatx4*)(resid + obase + (size_t)k * 16);
        *(floatx4*)((float*)outv + obase + (size_t)k * 16) = v;
      }
      if (p == 0) __syncthreads();
    }
  }
}

// ---- Kernel 3a: partial S over an N-slice -> spart[p][bh][64][64] f32 ----
// grid (NH_, Bc, NSPL), block 256
__global__ __launch_bounds__(256) void qk_partial(const u16* __restrict__ qkv,
    float* __restrict__ spart, int nbh) {
  int h = blockIdx.x, bz = blockIdx.y, p = blockIdx.z;
  const u16* qb = qkv + ((size_t)bz * MQKV + h * HD_) * N_;
  const u16* kb = qkv + ((size_t)bz * MQKV + C_ + h * HD_) * N_;
  int tid = threadIdx.x, lane = tid & 63, wid = tid >> 6;
  int quad = lane >> 4, l15 = lane & 15;
  floatx4 acc[4][4];
#pragma unroll
  for (int i = 0; i < 4; ++i)
#pragma unroll
    for (int j = 0; j < 4; ++j) acc[i][j] = (floatx4)0.f;

  for (int ks = 0; ks < 4; ++ks) {
    int n = p * 512 + wid * 128 + ks * 32 + quad * 8;
    short8 af[4], bf8[4];
#pragma unroll
    for (int mi = 0; mi < 4; ++mi)
      af[mi] = *(const short8*)(qb + (size_t)(mi * 16 + l15) * N_ + n);
#pragma unroll
    for (int ni = 0; ni < 4; ++ni)
      bf8[ni] = *(const short8*)(kb + (size_t)(ni * 16 + l15) * N_ + n);
#pragma unroll
    for (int mi = 0; mi < 4; ++mi)
#pragma unroll
      for (int ni = 0; ni < 4; ++ni)
        acc[mi][ni] = __builtin_amdgcn_mfma_f32_16x16x32_bf16(af[mi], bf8[ni], acc[mi][ni], 0, 0, 0);
  }
  __shared__ float S[64 * 68];
  for (int i = tid; i < 64 * 68; i += 256) S[i] = 0.f;
  __syncthreads();
#pragma unroll
  for (int mi = 0; mi < 4; ++mi)
#pragma unroll
    for (int ni = 0; ni < 4; ++ni)
#pragma unroll
      for (int r = 0; r < 4; ++r)
        atomicAdd(&S[(mi * 16 + quad * 4 + r) * 68 + ni * 16 + l15], acc[mi][ni][r]);
  __syncthreads();
  int bh = bz * NH_ + h;
  float* dst = spart + ((size_t)p * nbh + bh) * 4096 + tid * 16;
  int row = tid >> 2, c0 = (tid & 3) * 16;
#pragma unroll
  for (int j = 0; j < 4; ++j)
    *(floatx4*)(dst + j * 4) = *(const floatx4*)&S[row * 68 + c0 + j * 4];
}

// ---- Kernel 3b: sum partials + row softmax (one lane per row) ----
// grid (Bc*NH_), block 64
__global__ __launch_bounds__(64) void softmax_rows(const float* __restrict__ spart,
    float* __restrict__ attn, int nbh) {
  int bh = blockIdx.x, c = threadIdx.x;
  const float* sp = spart + (size_t)bh * 4096 + c * 64;
  floatx4 row4[16];
#pragma unroll
  for (int j = 0; j < 16; ++j) row4[j] = *(const floatx4*)(sp + j * 4);
#pragma unroll
  for (int p = 1; p < NSPL; ++p) {
    const float* spp = sp + (size_t)p * nbh * 4096;
#pragma unroll
    for (int j = 0; j < 16; ++j) row4[j] += *(const floatx4*)(spp + j * 4);
  }
  float mx = -1e30f;
#pragma unroll
  for (int j = 0; j < 16; ++j)
#pragma unroll
    for (int e = 0; e < 4; ++e) mx = fmaxf(mx, row4[j][e]);
  float sum = 0.f;
#pragma unroll
  for (int j = 0; j < 16; ++j)
#pragma unroll
    for (int e = 0; e < 4; ++e) {
      float ev = __expf((row4[j][e] - mx) * 0.125f);
      row4[j][e] = ev; sum += ev;
    }
  float inv = 1.f / sum;
  float* dst = attn + (size_t)bh * 4096 + c * 64;
#pragma unroll
  for (int j = 0; j < 16; ++j) *(floatx4*)(dst + j * 4) = row4[j] * inv;
}

// ------- Kernel 4: O = attn * v, output TRANSPOSED ot[bz][n][c] bf16 (c = h*64+hd) -----
__global__ __launch_bounds__(256) void pv_kernel(const float* __restrict__ attn,
    const u16* __restrict__ qkv, u16* __restrict__ ot) {
  int nt = blockIdx.x, h = blockIdx.y, bz = blockIdx.z;
  int n0 = nt * 256;
  const u16* vb = qkv + ((size_t)bz * MQKV + 2 * C_ + h * HD_) * N_;
  __shared__ alignas(16) u16 Ps[64 * 72];
  __shared__ alignas(16) u16 Vs[256 * 72];
  int tid = threadIdx.x, lane = tid & 63, wid = tid >> 6;
  int quad = lane >> 4, l15 = lane & 15;
  const float* ab = attn + (size_t)(bz * NH_ + h) * 4096;
#pragma unroll
  for (int i = 0; i < 16; ++i) {
    int idx = tid + i * 256;
    int row = idx >> 6, col = idx & 63;
    Ps[row * 72 + col] = f2bf(ab[idx]);
  }
#pragma unroll
  for (int i = 0; i < 8; ++i) {
    int l = tid + i * 256;
    int ch = l >> 5, n8 = (l & 31) * 8;
    V16 v; v.u = *(const uintx4*)(vb + (size_t)ch * N_ + n0 + n8);
    int chunk = ch >> 3, clo = ch & 7;
#pragma unroll
    for (int j = 0; j < 8; ++j) {
      int nl = n8 + j;
      Vs[nl * 72 + (chunk ^ ((nl >> 3) & 7)) * 8 + clo] = v.s[j];
    }
  }
  __syncthreads();
  floatx4 acc[4][4];
#pragma unroll
  for (int i = 0; i < 4; ++i)
#pragma unroll
    for (int j = 0; j < 4; ++j) acc[i][j] = (floatx4)0.f;
#pragma unroll
  for (int ks = 0; ks < 2; ++ks) {
    short8 af[4], bf8[4];
    int ko = ks * 32 + quad * 8;
#pragma unroll
    for (int mi = 0; mi < 4; ++mi)
      af[mi] = *(const short8*)&Ps[(mi * 16 + l15) * 72 + ko];
    int chunk = ks * 4 + quad;
#pragma unroll
    for (int ni = 0; ni < 4; ++ni) {
      int nl = wid * 64 + ni * 16 + l15;
      bf8[ni] = *(const short8*)&Vs[nl * 72 + (chunk ^ ((nl >> 3) & 7)) * 8];
    }
#pragma unroll
    for (int mi = 0; mi < 4; ++mi)
#pragma unroll
      for (int ni = 0; ni < 4; ++ni)
        acc[mi][ni] = __builtin_amdgcn_mfma_f32_16x16x32_bf16(af[mi], bf8[ni], acc[mi][ni], 0, 0, 0);
  }
  __syncthreads();
  u16* Ls = Vs;
#pragma unroll
  for (int mi = 0; mi < 4; ++mi)
#pragma unroll
    for (int ni = 0; ni < 4; ++ni)
#pragma unroll
      for (int r = 0; r < 4; ++r) {
        int n  = wid * 64 + ni * 16 + l15;
        int hd = mi * 16 + quad * 4 + r;
        Ls[n * 64 + (((hd >> 3) ^ (n & 7)) * 8) + (hd & 7)] = f2bf(acc[mi][ni][r]);
      }
  __syncthreads();
  uintx4* dst = (uintx4*)(ot + ((size_t)bz * N_ + n0 + tid) * C_ + h * HD_);
#pragma unroll
  for (int k = 0; k < 8; ++k) {
    int kc = k ^ (tid & 7);
    dst[k] = *(const uintx4*)&Ls[tid * 64 + kc * 8];
  }
}

extern "C" void kernel_launch(void* const* d_in, const int* in_sizes, int n_in,
                              void* d_out, int out_size, void* d_ws, size_t ws_size,
                              hipStream_t stream) {
  const float* x      = (const float*)d_in[0];
  const float* gamma  = (const float*)d_in[1];
  const float* beta   = (const float*)d_in[2];
  const float* w_qkv  = (const float*)d_in[3];
  const float* b_qkv  = (const float*)d_in[4];
  const float* w_proj = (const float*)d_in[5];
  const float* b_proj = (const float*)d_in[6];
  float* out = (float*)d_out;

  // ws: s[16*512]f32 | t[16*512]f32 | wq bf16 | wp bf16 | attn[Bc*8*64*64]f32 |
  //     xt[Bc*4096*512]bf16 (aliased: spart after QKV gemm, o_t after softmax) |
  //     qkv[Bc*1536*4096]bf16
  const size_t fixed = (size_t)2 * B_ * C_ * 4 + (size_t)(MQKV + C_) * C_ * 2;
  const size_t per_batch = (size_t)NH_ * 64 * 64 * 4 + (size_t)N_ * C_ * 2 + (size_t)MQKV * N_ * 2;
  int Bc = 16;
  while (Bc > 1 && fixed + (size_t)Bc * per_batch > ws_size) Bc >>= 1;

  float* s_arr = (float*)d_ws;
  float* t_arr = s_arr + B_ * C_;
  u16* wq = (u16*)(t_arr + B_ * C_);
  u16* wp = wq + MQKV * C_;
  float* attn = (float*)(wp + C_ * C_);
  u16* xt  = (u16*)(attn + (size_t)Bc * NH_ * 64 * 64);
  u16* qkv = xt + (size_t)Bc * N_ * C_;
  float* spart = (float*)xt;  // xt dead between QKV gemm and pv; NSPL*Bc*8*16KB <= Bc*4MB

  gn_stats<<<dim3(B_ * 32), dim3(256), 0, stream>>>(x, gamma, beta, s_arr, t_arr);
  cvt_bf16<<<dim3(MQKV * C_ / 2048), dim3(256), 0, stream>>>(w_qkv, wq);
  cvt_bf16<<<dim3(C_ * C_ / 2048), dim3(256), 0, stream>>>(w_proj, wp);

  for (int b0 = 0; b0 < B_; b0 += Bc) {
    int nbh = Bc * NH_;
    gn_apply_t<<<dim3(N_ / 64, C_ / 64, Bc), dim3(256), 0, stream>>>(
        x + (size_t)b0 * C_ * N_, s_arr, t_arr, xt, b0);
    gemm_bt<<<dim3(32, 12, Bc), dim3(256), 0, stream>>>(
        wq, xt, b_qkv, nullptr, qkv, MQKV, 0, 0);
    qk_partial<<<dim3(NH_, Bc, NSPL), dim3(256), 0, stream>>>(qkv, spart, nbh);
    softmax_rows<<<dim3(nbh), dim3(64), 0, stream>>>(spart, attn, nbh);
    pv_kernel<<<dim3(16, NH_, Bc), dim3(256), 0, stream>>>(attn, qkv, xt);  // xt := o_t
    gemm_bt<<<dim3(32, 4, Bc), dim3(256), 0, stream>>>(
        wp, xt, b_proj, x + (size_t)b0 * C_ * N_, out + (size_t)b0 * C_ * N_, C_, 1, 1);
  }
}

// Round 6
// 679.645 us; speedup vs baseline: 1.4873x; 1.0273x over previous
//
#include <hip/hip_runtime.h>

typedef unsigned short u16;
typedef __attribute__((ext_vector_type(8))) short short8;
typedef __attribute__((ext_vector_type(4))) float floatx4;
typedef __attribute__((ext_vector_type(4))) unsigned int uintx4;

#define B_    16
#define C_    512
#define N_    4096
#define NH_   8
#define HD_   64
#define MQKV  1536
#define NSPL  8

union V16 { uintx4 u; u16 s[8]; short8 h; };

__device__ inline u16 f2bf(float f) {
  union { float f; unsigned int i; } c; c.f = f;
  unsigned int i = c.i;
  return (u16)((i + 0x7FFFu + ((i >> 16) & 1u)) >> 16);
}

// async global->LDS, 16B per lane; LDS dest must be wave-uniform-base + lane*16
__device__ __forceinline__ void gld16(const u16* g, u16* l) {
  __builtin_amdgcn_global_load_lds(
      (const __attribute__((address_space(1))) unsigned int*)g,
      (__attribute__((address_space(3))) unsigned int*)l, 16, 0, 0);
}

// ---------------- Kernel 1: GroupNorm stats -> per-(b,c) affine (f32 in) ----------------
__global__ __launch_bounds__(256) void gn_stats(const float* __restrict__ x,
    const float* __restrict__ gamma, const float* __restrict__ beta,
    float* __restrict__ s_arr, float* __restrict__ t_arr) {
  int b = blockIdx.x >> 5, g = blockIdx.x & 31;
  const floatx4* p = (const floatx4*)(x + (size_t)(b * C_ + g * 16) * N_);
  int tid = threadIdx.x;
  float sum = 0.f, ssq = 0.f;
  for (int it = 0; it < 64; ++it) {
    floatx4 v = p[tid + it * 256];
#pragma unroll
    for (int j = 0; j < 4; ++j) { float f = v[j]; sum += f; ssq += f * f; }
  }
#pragma unroll
  for (int off = 32; off > 0; off >>= 1) {
    sum += __shfl_down(sum, off);
    ssq += __shfl_down(ssq, off);
  }
  __shared__ float red[8];
  __shared__ float mv[2];
  int lane = tid & 63, wid = tid >> 6;
  if (lane == 0) { red[wid] = sum; red[wid + 4] = ssq; }
  __syncthreads();
  if (tid == 0) {
    float s = red[0] + red[1] + red[2] + red[3];
    float q = red[4] + red[5] + red[6] + red[7];
    float mean = s * (1.f / 65536.f);
    float var  = q * (1.f / 65536.f) - mean * mean;
    mv[0] = mean; mv[1] = rsqrtf(var + 1e-5f);
  }
  __syncthreads();
  if (tid < 16) {
    int c = g * 16 + tid;
    float ga = gamma[c], be = beta[c];
    float mean = mv[0], rstd = mv[1];
    s_arr[b * C_ + c] = ga * rstd;
    t_arr[b * C_ + c] = be - mean * rstd * ga;
  }
}

// ---------------- Kernel 1b: f32 -> bf16 convert (weights, one-time) ----------------
__global__ __launch_bounds__(256) void cvt_bf16(const float* __restrict__ src,
                                                u16* __restrict__ dst) {
  int i = blockIdx.x * 256 + threadIdx.x;
  const floatx4* s4 = (const floatx4*)src;
  floatx4 a = s4[2 * i], b = s4[2 * i + 1];
  V16 v;
#pragma unroll
  for (int j = 0; j < 4; ++j) { v.s[j] = f2bf(a[j]); v.s[4 + j] = f2bf(b[j]); }
  ((uintx4*)dst)[i] = v.u;
}

// ---- Kernel 1c: GN-apply + transpose: x[b][c][n] f32 -> xt[b][n][c] bf16 ----
__global__ __launch_bounds__(256) void gn_apply_t(const float* __restrict__ x,
    const float* __restrict__ s_arr, const float* __restrict__ t_arr,
    u16* __restrict__ xt, int b0) {
  __shared__ float T[64][65];
  int bz = blockIdx.z, gb = b0 + bz;
  int n0 = blockIdx.x * 64, c0 = blockIdx.y * 64;
  int tid = threadIdx.x;
  int cl = tid >> 4;
  int nl = (tid & 15) * 4;
  const float* xb = x + (size_t)bz * C_ * N_;
#pragma unroll
  for (int ci = 0; ci < 4; ++ci) {
    int c = c0 + cl + ci * 16;
    float s = s_arr[gb * C_ + c], t = t_arr[gb * C_ + c];
    floatx4 v = *(const floatx4*)(xb + (size_t)c * N_ + n0 + nl);
#pragma unroll
    for (int j = 0; j < 4; ++j) T[cl + ci * 16][nl + j] = s * v[j] + t;
  }
  __syncthreads();
  int n = tid >> 2, cc = (tid & 3) * 16;
  V16 a, b;
#pragma unroll
  for (int j = 0; j < 8; ++j) a.s[j] = f2bf(T[cc + j][n]);
#pragma unroll
  for (int j = 0; j < 8; ++j) b.s[j] = f2bf(T[cc + 8 + j][n]);
  uintx4* dst = (uintx4*)(xt + (size_t)bz * N_ * C_ + (size_t)(n0 + n) * C_ + c0 + cc);
  dst[0] = a.u; dst[1] = b.u;
}

// ------- Kernel 2/5: out[bz][m][n] = A[m][k] * B[bz][n][k]^T  (both bf16 k-contig) ----
// 128x128 tile, global_load_lds w16, source-side XOR swizzle.
// T3 2-phase pipeline: LDS double-buffer, prefetch kt+1 issued before compute(kt),
// single vmcnt(0)+s_barrier per K-step AFTER the MFMAs (load latency hides under compute).
__global__ __launch_bounds__(256) void gemm_bt(
    const u16* __restrict__ A, const u16* __restrict__ Bm,
    const float* __restrict__ bias, const float* __restrict__ resid,
    void* __restrict__ outv, int M, int doRes, int outF32) {
  __shared__ alignas(16) u16 smem[2 * 2 * 128 * 64];   // [buf][As|Bs]; epilogue reuses
  int bz = blockIdx.z;
  int m0 = blockIdx.y * 128, n0 = blockIdx.x * 128;
  int tid = threadIdx.x, lane = tid & 63, wid = tid >> 6;
  int quad = lane >> 4, l15 = lane & 15;
  int wm = (wid >> 1) * 64, wn = (wid & 1) * 64;
  int sr = tid >> 3, sc = tid & 7;
  const u16* Bb = Bm + (size_t)bz * ((size_t)N_ * C_);
  floatx4 acc[4][4];
#pragma unroll
  for (int i = 0; i < 4; ++i)
#pragma unroll
    for (int j = 0; j < 4; ++j) acc[i][j] = (floatx4)0.f;

  // stage tile kt into buffer p (LDS linear, global source pre-swizzled chunk^=row&7)
  auto stage = [&](int kt, int p) {
    u16* As = smem + p * 16384;
    u16* Bs = As + 8192;
#pragma unroll
    for (int i = 0; i < 4; ++i) {
      int rr = sr + i * 32;
      int cc = sc ^ (rr & 7);
      gld16(A  + (size_t)(m0 + rr) * C_ + kt * 64 + cc * 8, &As[rr * 64 + sc * 8]);
      gld16(Bb + (size_t)(n0 + rr) * C_ + kt * 64 + cc * 8, &Bs[rr * 64 + sc * 8]);
    }
  };

  stage(0, 0);
  asm volatile("s_waitcnt vmcnt(0)" ::: "memory");
  __builtin_amdgcn_s_barrier();
  int cur = 0;
  for (int kt = 0; kt < 8; ++kt) {
    if (kt < 7) stage(kt + 1, cur ^ 1);   // prefetch next tile (in flight during MFMAs)
    const u16* As = smem + cur * 16384;
    const u16* Bs = As + 8192;
#pragma unroll
    for (int ks = 0; ks < 2; ++ks) {
      short8 af[4], bf8[4];
#pragma unroll
      for (int mi = 0; mi < 4; ++mi) {
        int row = wm + mi * 16 + l15;
        int kc = (ks * 4 + quad) ^ (row & 7);
        af[mi] = *(const short8*)&As[row * 64 + kc * 8];
      }
#pragma unroll
      for (int ni = 0; ni < 4; ++ni) {
        int row = wn + ni * 16 + l15;
        int kc = (ks * 4 + quad) ^ (row & 7);
        bf8[ni] = *(const short8*)&Bs[row * 64 + kc * 8];
      }
#pragma unroll
      for (int mi = 0; mi < 4; ++mi)
#pragma unroll
        for (int ni = 0; ni < 4; ++ni)
          acc[mi][ni] = __builtin_amdgcn_mfma_f32_16x16x32_bf16(af[mi], bf8[ni], acc[mi][ni], 0, 0, 0);
    }
    asm volatile("s_waitcnt vmcnt(0)" ::: "memory");  // prefetch landed (hidden under MFMA)
    __builtin_amdgcn_s_barrier();                     // all waves done reading buf[cur]
    cur ^= 1;
  }
  // ---- epilogue: LDS transpose -> vectorized 16B global stores ----
  if (!outF32) {
    // bf16 out: 128x128 u16 tile, 16B-chunk XOR swizzle (chunk^(row&7) in low 3 bits)
    u16* E = smem;
#pragma unroll
    for (int mi = 0; mi < 4; ++mi)
#pragma unroll
      for (int ni = 0; ni < 4; ++ni)
#pragma unroll
        for (int r = 0; r < 4; ++r) {
          int row = wm + mi * 16 + quad * 4 + r;
          int col = wn + ni * 16 + l15;
          int ch = col >> 3;
          int cs = (ch & 8) | ((ch & 7) ^ (row & 7));
          E[row * 128 + cs * 8 + (col & 7)] = f2bf(acc[mi][ni][r] + bias[m0 + row]);
        }
    __syncthreads();
    int row = tid >> 1, half = tid & 1;
    u16* orow = (u16*)outv + ((size_t)bz * M + m0 + row) * N_ + n0 + half * 64;
#pragma unroll
    for (int k = 0; k < 8; ++k) {
      int cs = (half * 8) | (k ^ (row & 7));
      *(uintx4*)(orow + k * 8) = *(const uintx4*)&E[row * 128 + cs * 8];
    }
  } else {
    // f32 out: two passes of 64 rows x 128 cols (32 KB each), 16B-chunk XOR swizzle
    float* E = (float*)smem;
#pragma unroll
    for (int p = 0; p < 2; ++p) {
#pragma unroll
      for (int q = 0; q < 2; ++q)
#pragma unroll
        for (int ni = 0; ni < 4; ++ni)
#pragma unroll
          for (int r = 0; r < 4; ++r) {
            int mi = p * 2 + q;
            int lr = (wid >> 1) * 32 + q * 16 + quad * 4 + r;
            int col = wn + ni * 16 + l15;
            int ch = col >> 2;
            int cs = (ch & ~7) | ((ch & 7) ^ (lr & 7));
            E[lr * 128 + cs * 4 + (col & 3)] =
                acc[mi][ni][r] + bias[m0 + wm + mi * 16 + quad * 4 + r];
          }
      __syncthreads();
      // store: 64 rows x 128 cols, 256 threads -> row = tid>>2, 8 x float4 each
      int lr = tid >> 2, qt = tid & 3;
      int o = m0 + (lr >> 5) * 64 + p * 32 + (lr & 31);
      size_t obase = ((size_t)bz * M + o) * N_ + n0 + qt * 4;
#pragma unroll
      for (int k = 0; k < 8; ++k) {
        int ch = k * 4 + qt;
        int cs = (ch & ~7) | ((ch & 7) ^ (lr & 7));
        floatx4 v = *(const floatx4*)&E[lr * 128 + cs * 4];
        if (doRes) v += *(const floatx4*)(resid + obase + (size_t)k * 16);
        *(floatx4*)((float*)outv + obase + (size_t)k * 16) = v;
      }
      if (p == 0) __syncthreads();
    }
  }
}

// ---- Kernel 3a: partial S over an N-slice -> spart[p][bh][64][64] f32 ----
// grid (NH_, Bc, NSPL), block 256
__global__ __launch_bounds__(256) void qk_partial(const u16* __restrict__ qkv,
    float* __restrict__ spart, int nbh) {
  int h = blockIdx.x, bz = blockIdx.y, p = blockIdx.z;
  const u16* qb = qkv + ((size_t)bz * MQKV + h * HD_) * N_;
  const u16* kb = qkv + ((size_t)bz * MQKV + C_ + h * HD_) * N_;
  int tid = threadIdx.x, lane = tid & 63, wid = tid >> 6;
  int quad = lane >> 4, l15 = lane & 15;
  floatx4 acc[4][4];
#pragma unroll
  for (int i = 0; i < 4; ++i)
#pragma unroll
    for (int j = 0; j < 4; ++j) acc[i][j] = (floatx4)0.f;

  for (int ks = 0; ks < 4; ++ks) {
    int n = p * 512 + wid * 128 + ks * 32 + quad * 8;
    short8 af[4], bf8[4];
#pragma unroll
    for (int mi = 0; mi < 4; ++mi)
      af[mi] = *(const short8*)(qb + (size_t)(mi * 16 + l15) * N_ + n);
#pragma unroll
    for (int ni = 0; ni < 4; ++ni)
      bf8[ni] = *(const short8*)(kb + (size_t)(ni * 16 + l15) * N_ + n);
#pragma unroll
    for (int mi = 0; mi < 4; ++mi)
#pragma unroll
      for (int ni = 0; ni < 4; ++ni)
        acc[mi][ni] = __builtin_amdgcn_mfma_f32_16x16x32_bf16(af[mi], bf8[ni], acc[mi][ni], 0, 0, 0);
  }
  __shared__ float S[64 * 68];
  for (int i = tid; i < 64 * 68; i += 256) S[i] = 0.f;
  __syncthreads();
#pragma unroll
  for (int mi = 0; mi < 4; ++mi)
#pragma unroll
    for (int ni = 0; ni < 4; ++ni)
#pragma unroll
      for (int r = 0; r < 4; ++r)
        atomicAdd(&S[(mi * 16 + quad * 4 + r) * 68 + ni * 16 + l15], acc[mi][ni][r]);
  __syncthreads();
  int bh = bz * NH_ + h;
  float* dst = spart + ((size_t)p * nbh + bh) * 4096 + tid * 16;
  int row = tid >> 2, c0 = (tid & 3) * 16;
#pragma unroll
  for (int j = 0; j < 4; ++j)
    *(floatx4*)(dst + j * 4) = *(const floatx4*)&S[row * 68 + c0 + j * 4];
}

// ---- Kernel 3b: sum partials + row softmax (one lane per row) ----
// grid (Bc*NH_), block 64
__global__ __launch_bounds__(64) void softmax_rows(const float* __restrict__ spart,
    float* __restrict__ attn, int nbh) {
  int bh = blockIdx.x, c = threadIdx.x;
  const float* sp = spart + (size_t)bh * 4096 + c * 64;
  floatx4 row4[16];
#pragma unroll
  for (int j = 0; j < 16; ++j) row4[j] = *(const floatx4*)(sp + j * 4);
#pragma unroll
  for (int p = 1; p < NSPL; ++p) {
    const float* spp = sp + (size_t)p * nbh * 4096;
#pragma unroll
    for (int j = 0; j < 16; ++j) row4[j] += *(const floatx4*)(spp + j * 4);
  }
  float mx = -1e30f;
#pragma unroll
  for (int j = 0; j < 16; ++j)
#pragma unroll
    for (int e = 0; e < 4; ++e) mx = fmaxf(mx, row4[j][e]);
  float sum = 0.f;
#pragma unroll
  for (int j = 0; j < 16; ++j)
#pragma unroll
    for (int e = 0; e < 4; ++e) {
      float ev = __expf((row4[j][e] - mx) * 0.125f);
      row4[j][e] = ev; sum += ev;
    }
  float inv = 1.f / sum;
  float* dst = attn + (size_t)bh * 4096 + c * 64;
#pragma unroll
  for (int j = 0; j < 16; ++j) *(floatx4*)(dst + j * 4) = row4[j] * inv;
}

// ------- Kernel 4: O = attn * v, output TRANSPOSED ot[bz][n][c] bf16 (c = h*64+hd) -----
__global__ __launch_bounds__(256) void pv_kernel(const float* __restrict__ attn,
    const u16* __restrict__ qkv, u16* __restrict__ ot) {
  int nt = blockIdx.x, h = blockIdx.y, bz = blockIdx.z;
  int n0 = nt * 256;
  const u16* vb = qkv + ((size_t)bz * MQKV + 2 * C_ + h * HD_) * N_;
  __shared__ alignas(16) u16 Ps[64 * 72];
  __shared__ alignas(16) u16 Vs[256 * 72];
  int tid = threadIdx.x, lane = tid & 63, wid = tid >> 6;
  int quad = lane >> 4, l15 = lane & 15;
  const float* ab = attn + (size_t)(bz * NH_ + h) * 4096;
#pragma unroll
  for (int i = 0; i < 16; ++i) {
    int idx = tid + i * 256;
    int row = idx >> 6, col = idx & 63;
    Ps[row * 72 + col] = f2bf(ab[idx]);
  }
#pragma unroll
  for (int i = 0; i < 8; ++i) {
    int l = tid + i * 256;
    int ch = l >> 5, n8 = (l & 31) * 8;
    V16 v; v.u = *(const uintx4*)(vb + (size_t)ch * N_ + n0 + n8);
    int chunk = ch >> 3, clo = ch & 7;
#pragma unroll
    for (int j = 0; j < 8; ++j) {
      int nl = n8 + j;
      Vs[nl * 72 + (chunk ^ ((nl >> 3) & 7)) * 8 + clo] = v.s[j];
    }
  }
  __syncthreads();
  floatx4 acc[4][4];
#pragma unroll
  for (int i = 0; i < 4; ++i)
#pragma unroll
    for (int j = 0; j < 4; ++j) acc[i][j] = (floatx4)0.f;
#pragma unroll
  for (int ks = 0; ks < 2; ++ks) {
    short8 af[4], bf8[4];
    int ko = ks * 32 + quad * 8;
#pragma unroll
    for (int mi = 0; mi < 4; ++mi)
      af[mi] = *(const short8*)&Ps[(mi * 16 + l15) * 72 + ko];
    int chunk = ks * 4 + quad;
#pragma unroll
    for (int ni = 0; ni < 4; ++ni) {
      int nl = wid * 64 + ni * 16 + l15;
      bf8[ni] = *(const short8*)&Vs[nl * 72 + (chunk ^ ((nl >> 3) & 7)) * 8];
    }
#pragma unroll
    for (int mi = 0; mi < 4; ++mi)
#pragma unroll
      for (int ni = 0; ni < 4; ++ni)
        acc[mi][ni] = __builtin_amdgcn_mfma_f32_16x16x32_bf16(af[mi], bf8[ni], acc[mi][ni], 0, 0, 0);
  }
  __syncthreads();
  u16* Ls = Vs;
#pragma unroll
  for (int mi = 0; mi < 4; ++mi)
#pragma unroll
    for (int ni = 0; ni < 4; ++ni)
#pragma unroll
      for (int r = 0; r < 4; ++r) {
        int n  = wid * 64 + ni * 16 + l15;
        int hd = mi * 16 + quad * 4 + r;
        Ls[n * 64 + (((hd >> 3) ^ (n & 7)) * 8) + (hd & 7)] = f2bf(acc[mi][ni][r]);
      }
  __syncthreads();
  uintx4* dst = (uintx4*)(ot + ((size_t)bz * N_ + n0 + tid) * C_ + h * HD_);
#pragma unroll
  for (int k = 0; k < 8; ++k) {
    int kc = k ^ (tid & 7);
    dst[k] = *(const uintx4*)&Ls[tid * 64 + kc * 8];
  }
}

extern "C" void kernel_launch(void* const* d_in, const int* in_sizes, int n_in,
                              void* d_out, int out_size, void* d_ws, size_t ws_size,
                              hipStream_t stream) {
  const float* x      = (const float*)d_in[0];
  const float* gamma  = (const float*)d_in[1];
  const float* beta   = (const float*)d_in[2];
  const float* w_qkv  = (const float*)d_in[3];
  const float* b_qkv  = (const float*)d_in[4];
  const float* w_proj = (const float*)d_in[5];
  const float* b_proj = (const float*)d_in[6];
  float* out = (float*)d_out;

  // ws: s[16*512]f32 | t[16*512]f32 | wq bf16 | wp bf16 | attn[Bc*8*64*64]f32 |
  //     xt[Bc*4096*512]bf16 (aliased: spart after QKV gemm, o_t after softmax) |
  //     qkv[Bc*1536*4096]bf16
  const size_t fixed = (size_t)2 * B_ * C_ * 4 + (size_t)(MQKV + C_) * C_ * 2;
  const size_t per_batch = (size_t)NH_ * 64 * 64 * 4 + (size_t)N_ * C_ * 2 + (size_t)MQKV * N_ * 2;
  int Bc = 16;
  while (Bc > 1 && fixed + (size_t)Bc * per_batch > ws_size) Bc >>= 1;

  float* s_arr = (float*)d_ws;
  float* t_arr = s_arr + B_ * C_;
  u16* wq = (u16*)(t_arr + B_ * C_);
  u16* wp = wq + MQKV * C_;
  float* attn = (float*)(wp + C_ * C_);
  u16* xt  = (u16*)(attn + (size_t)Bc * NH_ * 64 * 64);
  u16* qkv = xt + (size_t)Bc * N_ * C_;
  float* spart = (float*)xt;  // xt dead between QKV gemm and pv; NSPL*Bc*8*16KB <= Bc*4MB

  gn_stats<<<dim3(B_ * 32), dim3(256), 0, stream>>>(x, gamma, beta, s_arr, t_arr);
  cvt_bf16<<<dim3(MQKV * C_ / 2048), dim3(256), 0, stream>>>(w_qkv, wq);
  cvt_bf16<<<dim3(C_ * C_ / 2048), dim3(256), 0, stream>>>(w_proj, wp);

  for (int b0 = 0; b0 < B_; b0 += Bc) {
    int nbh = Bc * NH_;
    gn_apply_t<<<dim3(N_ / 64, C_ / 64, Bc), dim3(256), 0, stream>>>(
        x + (size_t)b0 * C_ * N_, s_arr, t_arr, xt, b0);
    gemm_bt<<<dim3(32, 12, Bc), dim3(256), 0, stream>>>(
        wq, xt, b_qkv, nullptr, qkv, MQKV, 0, 0);
    qk_partial<<<dim3(NH_, Bc, NSPL), dim3(256), 0, stream>>>(qkv, spart, nbh);
    softmax_rows<<<dim3(nbh), dim3(64), 0, stream>>>(spart, attn, nbh);
    pv_kernel<<<dim3(16, NH_, Bc), dim3(256), 0, stream>>>(attn, qkv, xt);  // xt := o_t
    gemm_bt<<<dim3(32, 4, Bc), dim3(256), 0, stream>>>(
        wp, xt, b_proj, x + (size_t)b0 * C_ * N_, out + (size_t)b0 * C_ * N_, C_, 1, 1);
  }
}